// Round 12
// baseline (3370.623 us; speedup 1.0000x reference)
//
#include <hip/hip_runtime.h>
#include <math.h>

#define L 2048
#define B 8
#define D 1024
#define ND 16
#define BD (B*D)
#define CK 64                 // chunk length
#define NC (L/CK)             // 32 chunks
#define SZ ((size_t)B*NC*D*ND)        // floats per direction (16.8 MB)
#define NFLAGS (2*B*(D/64)*NC)        // 8192 chain flags
#define ZERON 8448                    // ints zeroed (flags + ticket + pad)

typedef float v2f __attribute__((ext_vector_type(2)));

__device__ __forceinline__ float sigmoid_precise(float v) {
    return 1.0f / (1.0f + expf(-v));
}
// fast sigmoid: v_exp + v_rcp (~3e-7 rel err; tolerance is 0.0625 abs)
__device__ __forceinline__ float sigmoid_fast(float v) {
    return __builtin_amdgcn_rcpf(1.0f + __expf(-v));
}

// Per-mode decay packed as 8 x float2 (modes 2i,2i+1 in lanes .x/.y).
__device__ __forceinline__ void load_q2(const float* __restrict__ damp,
                                        const float* __restrict__ decay,
                                        int row, v2f* q2) {
#pragma unroll
    for (int mg = 0; mg < 4; ++mg) {
        const float4 dp = reinterpret_cast<const float4*>(damp)[row * 4 + mg];
        const float4 dc = reinterpret_cast<const float4*>(decay)[row * 4 + mg];
        const float qa = 1.f - sigmoid_fast(dp.x) * sigmoid_fast(dc.x);
        const float qb = 1.f - sigmoid_fast(dp.y) * sigmoid_fast(dc.y);
        const float qc = 1.f - sigmoid_fast(dp.z) * sigmoid_fast(dc.z);
        const float qd = 1.f - sigmoid_fast(dp.w) * sigmoid_fast(dc.w);
        q2[2*mg+0] = (v2f){qa, qb};
        q2[2*mg+1] = (v2f){qc, qd};
    }
}

// Packed decay q2[8] and output coefficient c2[8] (= p * ema * proj / sqrt(ND)).
__device__ __forceinline__ void load_qc2(const float* __restrict__ damp,
                                         const float* __restrict__ decay,
                                         const float* __restrict__ ema,
                                         const float* __restrict__ proj,
                                         int row, v2f* q2, v2f* c2) {
#pragma unroll
    for (int mg = 0; mg < 4; ++mg) {
        const float4 dp = reinterpret_cast<const float4*>(damp)[row * 4 + mg];
        const float4 dc = reinterpret_cast<const float4*>(decay)[row * 4 + mg];
        const float4 em = reinterpret_cast<const float4*>(ema)[row * 4 + mg];
        const float4 pj = reinterpret_cast<const float4*>(proj)[row * 4 + mg];
        const float p0 = sigmoid_fast(dp.x), p1 = sigmoid_fast(dp.y),
                    p2 = sigmoid_fast(dp.z), p3 = sigmoid_fast(dp.w);
        q2[2*mg+0] = (v2f){1.f - p0 * sigmoid_fast(dc.x), 1.f - p1 * sigmoid_fast(dc.y)};
        q2[2*mg+1] = (v2f){1.f - p2 * sigmoid_fast(dc.z), 1.f - p3 * sigmoid_fast(dc.w)};
        c2[2*mg+0] = (v2f){p0 * em.x * pj.x * 0.25f, p1 * em.y * pj.y * 0.25f};
        c2[2*mg+1] = (v2f){p2 * em.z * pj.z * 0.25f, p3 * em.w * pj.w * 0.25f};
    }
}

// ---------------- flag zeroing (graph-capture-safe, replayed each iteration) --
__global__ void zero_flags_kernel(int* __restrict__ p) {
    p[blockIdx.x * 256 + threadIdx.x] = 0;
}

// ---------------- Fused Phase A+B: local scan + ticketed decoupled lookback ---
// Grid 4096 x 128thr. Ticket tk (taken at block start; order = start order):
//   pos = tk>>7 (chain position), sub = tk&127 -> (b, dblk).
// Wave 0: fwd scan of chunk pos. Wave 1: bwd scan of MIRROR chunk NC-1-pos.
// Both chains ascend with ticket -> a block only waits on smaller tickets
// (already started) -> deadlock-free regardless of dispatch order (G16).
// Publishes INCLUSIVE prefix/suffix at the chunk's natural slot:
//   fwdP[slot c] = prefix through chunk c ; bwdP[slot c] = suffix from chunk c.
__global__ __launch_bounds__(128, 2) void ema_scan_fused(
    const float* __restrict__ x, const float* __restrict__ damp,
    const float* __restrict__ decay, const int* __restrict__ mask,
    float* __restrict__ fwdP, float* __restrict__ bwdP,
    int* __restrict__ flags, int* __restrict__ ticket)
{
    __shared__ float smask[2][CK];
    __shared__ int s_tk;
    const int t    = threadIdx.x;
    const int lane = t & 63;
    const int wid  = t >> 6;               // 0 = fwd, 1 = bwd
    if (t == 0) s_tk = atomicAdd(ticket, 1);
    __syncthreads();
    const int tk   = s_tk;
    const int pos  = tk >> 7;              // chain position 0..NC-1
    const int sub  = tk & 127;
    const int b    = sub >> 4;
    const int dblk = sub & 15;

    const int myc = wid ? (NC - 1 - pos) : pos;   // my chunk
    const int j0  = myc * CK;
    const int um  = wid ? (CK - 1) : 0;           // u = i ^ um
    const int d   = dblk * 64 + lane;

    // each wave stages its own chunk's mask row (no cross-wave use)
    smask[wid][lane] = (float)mask[(size_t)b * L + j0 + lane];

    const int row = wid ? (d + D) : d;
    v2f q2[8], st2[8];
    load_q2(damp, decay, row, q2);
#pragma unroll
    for (int k = 0; k < 8; ++k) st2[k] = (v2f){0.f, 0.f};

    const float* xp = x + (size_t)j0 * BD + (size_t)b * D + d;
    const float* sm = smask[wid];

    float xA[16], xB[16], xC[16];
#define FLOADG(XR, G) \
    _Pragma("unroll") \
    for (int v = 0; v < 16; ++v) { \
        const int u = ((G) + v) ^ um; \
        XR[v] = xp[(size_t)u * BD]; \
    }
#define FCOMPG(XR, G) \
    _Pragma("unroll") \
    for (int v = 0; v < 16; ++v) { \
        const int u = ((G) + v) ^ um; \
        const float xm = XR[v] * sm[u]; \
        const v2f xm2 = {xm, xm}; \
        _Pragma("unroll") \
        for (int k = 0; k < 8; ++k) st2[k] = q2[k] * st2[k] + xm2; \
    }
    FLOADG(xA, 0)
    FLOADG(xB, 16)
    FLOADG(xC, 32)
    FCOMPG(xA, 0)
    FLOADG(xA, 48)
    FCOMPG(xB, 16)
    FCOMPG(xC, 32)
    FCOMPG(xA, 48)
#undef FLOADG
#undef FCOMPG

    // q^CK per mode (6 squarings for CK=64)
    v2f qc[8];
#pragma unroll
    for (int k = 0; k < 8; ++k) {
        v2f qq = q2[k];
#pragma unroll
        for (int s = 0; s < 6; ++s) qq *= qq;
        qc[k] = qq;
    }

    float* P = wid ? bwdP : fwdP;
    int* const flagBase = flags + ((wid * B + b) * 16 + dblk) * NC;

    if (pos > 0) {
        // predecessor chain position pos-1 = chunk (fwd: myc-1, bwd: myc+1)
        const int predc = wid ? (myc + 1) : (myc - 1);
        while (__hip_atomic_load(&flagBase[pos - 1], __ATOMIC_ACQUIRE,
                                 __HIP_MEMORY_SCOPE_AGENT) == 0) {
            __builtin_amdgcn_s_sleep(2);
        }
        const float4* p4 = reinterpret_cast<const float4*>(P) +
                           ((size_t)(b * NC + predc) * D + d) * 4;
#pragma unroll
        for (int mg = 0; mg < 4; ++mg) {
            const float4 pv = p4[mg];
            st2[2*mg+0] = qc[2*mg+0] * (v2f){pv.x, pv.y} + st2[2*mg+0];
            st2[2*mg+1] = qc[2*mg+1] * (v2f){pv.z, pv.w} + st2[2*mg+1];
        }
    }

    // publish inclusive value at my chunk slot, then raise my flag
    float4* s4 = reinterpret_cast<float4*>(P) + ((size_t)(b * NC + myc) * D + d) * 4;
#pragma unroll
    for (int mg = 0; mg < 4; ++mg)
        s4[mg] = make_float4(st2[2*mg+0].x, st2[2*mg+0].y, st2[2*mg+1].x, st2[2*mg+1].y);
    __threadfence();
    if (lane == 0)
        __hip_atomic_store(&flagBase[pos], 1, __ATOMIC_RELEASE, __HIP_MEMORY_SCOPE_AGENT);
}

// ---------------- Fallback middle path: summary + inclusive prefix -----------
__global__ __launch_bounds__(128, 2) void ema_summary_kernel(
    const float* __restrict__ x, const float* __restrict__ damp,
    const float* __restrict__ decay, const int* __restrict__ mask,
    float* __restrict__ fwdS, float* __restrict__ bwdS)
{
    __shared__ float smask[CK];
    const int lane = threadIdx.x & 63;
    const int wid  = threadIdx.x >> 6;
    const int d  = blockIdx.x * 64 + lane;
    const int b  = blockIdx.y;
    const int ch = blockIdx.z;
    const int j0 = ch * CK;
    const int um = wid ? (CK - 1) : 0;

    const float* xp = x + (size_t)j0 * BD + (size_t)b * D + d;
    const int*   mp = mask + (size_t)b * L + j0;
    if (threadIdx.x < CK) smask[threadIdx.x] = (float)mp[threadIdx.x];
    __syncthreads();

    const int row = wid ? (d + D) : d;
    v2f q2[8], st2[8];
    load_q2(damp, decay, row, q2);
#pragma unroll
    for (int k = 0; k < 8; ++k) st2[k] = (v2f){0.f, 0.f};

    float xA[16], xB[16], xC[16];
#define SLOADG(XR, G) \
    _Pragma("unroll") \
    for (int v = 0; v < 16; ++v) { \
        const int u = ((G) + v) ^ um; \
        XR[v] = xp[(size_t)u * BD]; \
    }
#define SCOMPG(XR, G) \
    _Pragma("unroll") \
    for (int v = 0; v < 16; ++v) { \
        const int u = ((G) + v) ^ um; \
        const float xm = XR[v] * smask[u]; \
        const v2f xm2 = {xm, xm}; \
        _Pragma("unroll") \
        for (int k = 0; k < 8; ++k) st2[k] = q2[k] * st2[k] + xm2; \
    }
    SLOADG(xA, 0)
    SLOADG(xB, 16)
    SLOADG(xC, 32)
    SCOMPG(xA, 0)
    SLOADG(xA, 48)
    SCOMPG(xB, 16)
    SCOMPG(xC, 32)
    SCOMPG(xA, 48)
#undef SLOADG
#undef SCOMPG

    float* Sx = wid ? bwdS : fwdS;
    float4* s4 = reinterpret_cast<float4*>(Sx) + ((size_t)(b * NC + ch) * D + d) * 4;
#pragma unroll
    for (int mg = 0; mg < 4; ++mg)
        s4[mg] = make_float4(st2[2*mg+0].x, st2[2*mg+0].y, st2[2*mg+1].x, st2[2*mg+1].y);
}

// In-place E -> INCLUSIVE prefix (fwd) / suffix (bwd), matching fused layout.
__global__ __launch_bounds__(1024) void ema_prefix_kernel(
    const float* __restrict__ damp, const float* __restrict__ decay,
    float* __restrict__ fwdS, float* __restrict__ bwdS)
{
    const int tid = blockIdx.x * 1024 + threadIdx.x;
    const int m = tid & (ND - 1);
    const int d = (tid >> 4) & (D - 1);
    const int b = tid >> 14;
    const size_t CS = (size_t)D * ND;
    const size_t off = (size_t)b * NC * CS + (size_t)d * ND + m;
    float* fb = fwdS + off;
    float* bb = bwdS + off;

    const int idxf = d * ND + m;
    const int idxb = (d + D) * ND + m;
    float qf = 1.f - sigmoid_fast(damp[idxf]) * sigmoid_fast(decay[idxf]);
    float qb = 1.f - sigmoid_fast(damp[idxb]) * sigmoid_fast(decay[idxb]);
#pragma unroll
    for (int s = 0; s < 6; ++s) { qf *= qf; qb *= qb; }   // q^64

    float Ef[NC], Eb[NC];
#pragma unroll
    for (int i = 0; i < NC; ++i) Ef[i] = fb[(size_t)i * CS];
#pragma unroll
    for (int i = 0; i < NC; ++i) Eb[i] = bb[(size_t)i * CS];

    float F = 0.f, G = 0.f;
#pragma unroll
    for (int i = 0; i < NC; ++i) {
        F = fmaf(qf, F, Ef[i]);          fb[(size_t)i * CS] = F;          // inclusive
        G = fmaf(qb, G, Eb[NC-1-i]);     bb[(size_t)(NC-1-i) * CS] = G;   // inclusive suffix
    }
}

// ---------------- Phase C: apply (r9-proven; entry = neighbor inclusive slot) -
__global__ __launch_bounds__(128, 2) void ema_apply_kernel(
    const float* __restrict__ x, const float* __restrict__ damp,
    const float* __restrict__ decay, const float* __restrict__ ema,
    const float* __restrict__ proj, const float* __restrict__ rw,
    const int* __restrict__ mask,
    const float* __restrict__ fwdP, const float* __restrict__ bwdP,
    float* __restrict__ out)
{
    constexpr int HALF = CK / 2;
    __shared__ float hacc[2][HALF][64];      // 16 KB
    __shared__ float smask[CK];

    const int lane = threadIdx.x & 63;
    const int wid  = threadIdx.x >> 6;       // 0 = fwd, 1 = bwd
    const int d  = blockIdx.x * 64 + lane;
    const int b  = blockIdx.y;
    const int ch = blockIdx.z;
    const int j0 = ch * CK;
    const int um = wid ? (CK - 1) : 0;       // u = i ^ um

    const float* xp = x   + (size_t)j0 * BD + (size_t)b * D + d;
    float*       op = out + (size_t)j0 * BD + (size_t)b * D + d;
    const int*   mp = mask + (size_t)b * L + j0;
    if (threadIdx.x < CK) smask[threadIdx.x] = (float)mp[threadIdx.x];

    const int    row  = wid ? (d + D) : d;
    const float  weff = wid ? 0.f : rw[d];           // residual only on fwd wave
    const float* Sx   = wid ? bwdP : fwdP;

    v2f q2[8], c2[8], st2[8];
    load_qc2(damp, decay, ema, proj, row, q2, c2);
    // entry state: fwd chunk ch reads inclusive prefix slot ch-1;
    // bwd chunk ch reads inclusive suffix slot ch+1; boundary -> zeros.
    const int  eslot = wid ? (ch + 1) : (ch - 1);
    const bool ezero = wid ? (ch == NC - 1) : (ch == 0);
    if (!ezero) {
        const float4* s4 = reinterpret_cast<const float4*>(Sx) +
                           ((size_t)(b * NC + eslot) * D + d) * 4;
#pragma unroll
        for (int mg = 0; mg < 4; ++mg) {
            const float4 v = s4[mg];
            st2[2*mg+0] = (v2f){v.x, v.y};
            st2[2*mg+1] = (v2f){v.z, v.w};
        }
    } else {
#pragma unroll
        for (int k = 0; k < 8; ++k) st2[k] = (v2f){0.f, 0.f};
    }
    __syncthreads();   // smask visible

    float xA[16], xB[16], xC[16];

#define ALOADG(XR, G) \
    _Pragma("unroll") \
    for (int v = 0; v < 16; ++v) { \
        const int u = ((G) + v) ^ um; \
        XR[v] = xp[(size_t)u * BD]; \
    }
#define ASTEP(XR, V, G) \
    const int u = ((G) + (V)) ^ um; \
    const float xraw = XR[V]; \
    const float xm   = xraw * smask[u]; \
    const v2f xm2 = {xm, xm}; \
    _Pragma("unroll") \
    for (int k = 0; k < 8; ++k) st2[k] = q2[k] * st2[k] + xm2; \
    v2f a0 = c2[0] * st2[0], a1 = c2[1] * st2[1], \
        a2 = c2[2] * st2[2], a3 = c2[3] * st2[3]; \
    a0 = c2[4] * st2[4] + a0; \
    a1 = c2[5] * st2[5] + a1; \
    a2 = c2[6] * st2[6] + a2; \
    a3 = c2[7] * st2[7] + a3; \
    const v2f sres = (a0 + a1) + (a2 + a3);
#define ACOMP_LDS(XR, G) \
    _Pragma("unroll") \
    for (int v = 0; v < 16; ++v) { \
        ASTEP(XR, v, G) \
        hacc[wid][u & (HALF - 1)][lane] = fmaf(xraw, weff, sres.x + sres.y); \
    }
#define ACOMP_OUT(XR, G) \
    _Pragma("unroll") \
    for (int v = 0; v < 16; ++v) { \
        ASTEP(XR, v, G) \
        const float tv  = fmaf(xraw, weff, sres.x + sres.y); \
        const float val = tv + hacc[ow][u & (HALF - 1)][lane]; \
        op[(size_t)u * BD] = val * __builtin_amdgcn_rcpf(1.0f + __expf(-val)); \
    }

    // phase 1 (scan steps 0..31 -> LDS), with phase-2 loads already in flight
    ALOADG(xA, 0)
    ALOADG(xB, 16)
    ALOADG(xC, 32)
    ACOMP_LDS(xA, 0)
    ALOADG(xA, 48)
    ACOMP_LDS(xB, 16)
    __syncthreads();

    // phase 2 (scan steps 32..63): combine with other wave's half, silu, store
    const int ow = 1 - wid;
    ACOMP_OUT(xC, 32)
    ACOMP_OUT(xA, 48)
#undef ALOADG
#undef ASTEP
#undef ACOMP_LDS
#undef ACOMP_OUT
}

// ---------------- Fallback: validated single-pass scans ----------------------
template<int DIR>
__device__ __forceinline__ void ema_scan_body(
    const float* __restrict__ x, const float* __restrict__ damp,
    const float* __restrict__ decay, const float* __restrict__ ema,
    const float* __restrict__ proj, const float* __restrict__ rw,
    const int* __restrict__ mask, float* __restrict__ out)
{
    const int t  = threadIdx.x;
    const int ng = t & 3;
    const int dl = t >> 2;
    const int d  = blockIdx.x * 16 + dl;
    const int b  = blockIdx.y;
    const int row = (DIR == 0) ? d : (d + D);

    float q[4], c[4];
#pragma unroll
    for (int k = 0; k < 4; ++k) {
        const int idx = row * ND + ng * 4 + k;
        const float p  = sigmoid_precise(damp[idx]);
        const float sd = sigmoid_precise(decay[idx]);
        q[k] = 1.0f - p * sd;
        c[k] = p * ema[idx] * proj[idx] * 0.25f;
    }
    const float w = rw[d];
    const float* xp = x + (size_t)b * D + d;
    float*       op = out + (size_t)b * D + d;
    const int*   mp = mask + (size_t)b * L;
    float s0 = 0.f, s1 = 0.f, s2 = 0.f, s3 = 0.f;

    for (int jj = 0; jj < L; jj += 4) {
        float xv[4], mf[4];
#pragma unroll
        for (int u = 0; u < 4; ++u) {
            const int j = (DIR == 0) ? (jj + u) : (L - 1 - (jj + u));
            xv[u] = xp[(size_t)j * BD];
            mf[u] = (float)mp[j];
        }
        float acc[4];
#pragma unroll
        for (int u = 0; u < 4; ++u) {
            const float xm = xv[u] * mf[u];
            s0 = fmaf(q[0], s0, xm);
            s1 = fmaf(q[1], s1, xm);
            s2 = fmaf(q[2], s2, xm);
            s3 = fmaf(q[3], s3, xm);
            acc[u] = fmaf(c[1], s1, c[0] * s0) + fmaf(c[3], s3, c[2] * s2);
        }
#pragma unroll
        for (int u = 0; u < 4; ++u) acc[u] += __shfl_xor(acc[u], 1);
#pragma unroll
        for (int u = 0; u < 4; ++u) acc[u] += __shfl_xor(acc[u], 2);
        if (ng == 0) {
#pragma unroll
            for (int u = 0; u < 4; ++u) {
                const int j = (DIR == 0) ? (jj + u) : (L - 1 - (jj + u));
                const size_t oi = (size_t)j * BD;
                if (DIR == 0) op[oi] = fmaf(xv[u], w, acc[u]);
                else { const float v = op[oi] + acc[u]; op[oi] = v / (1.0f + expf(-v)); }
            }
        }
    }
}

__global__ __launch_bounds__(64) void ema_fwd_kernel(
    const float* __restrict__ x, const float* __restrict__ damp,
    const float* __restrict__ decay, const float* __restrict__ ema,
    const float* __restrict__ proj, const float* __restrict__ rw,
    const int* __restrict__ mask, float* __restrict__ out)
{ ema_scan_body<0>(x, damp, decay, ema, proj, rw, mask, out); }

__global__ __launch_bounds__(64) void ema_bwd_kernel(
    const float* __restrict__ x, const float* __restrict__ damp,
    const float* __restrict__ decay, const float* __restrict__ ema,
    const float* __restrict__ proj, const float* __restrict__ rw,
    const int* __restrict__ mask, float* __restrict__ out)
{ ema_scan_body<1>(x, damp, decay, ema, proj, rw, mask, out); }

// ---------------- driver -----------------------------------------------------
extern "C" void kernel_launch(void* const* d_in, const int* in_sizes, int n_in,
                              void* d_out, int out_size, void* d_ws, size_t ws_size,
                              hipStream_t stream) {
    (void)in_sizes; (void)n_in; (void)out_size;
    const float* x     = (const float*)d_in[0];
    const float* damp  = (const float*)d_in[1];
    const float* decay = (const float*)d_in[2];
    const float* ema   = (const float*)d_in[3];
    const float* proj  = (const float*)d_in[4];
    const float* rw    = (const float*)d_in[5];
    const int*   mask  = (const int*)d_in[6];
    float* out = (float*)d_out;

    const size_t stateBytes = 2 * SZ * sizeof(float);            // 33.6 MB
    const size_t fusedBytes = stateBytes + ZERON * sizeof(int);  // + 33 KB

    if (ws_size >= fusedBytes) {
        float* fwdP  = (float*)d_ws;
        float* bwdP  = fwdP + SZ;
        int*   flags = (int*)(bwdP + SZ);
        int*   tick  = flags + NFLAGS;
        (void)tick;
        zero_flags_kernel<<<dim3(ZERON / 256), dim3(256), 0, stream>>>(flags);
        ema_scan_fused<<<dim3(B * (D / 64) * NC), dim3(128), 0, stream>>>(
            x, damp, decay, mask, fwdP, bwdP, flags, flags + NFLAGS);
        ema_apply_kernel<<<dim3(D / 64, B, NC), dim3(128), 0, stream>>>(
            x, damp, decay, ema, proj, rw, mask, fwdP, bwdP, out);
    } else if (ws_size >= stateBytes) {
        float* fwdP = (float*)d_ws;
        float* bwdP = fwdP + SZ;
        dim3 g(D / 64, B, NC);
        ema_summary_kernel<<<g, dim3(128), 0, stream>>>(x, damp, decay, mask, fwdP, bwdP);
        ema_prefix_kernel<<<dim3((B * D * ND) / 1024), dim3(1024), 0, stream>>>(damp, decay, fwdP, bwdP);
        ema_apply_kernel<<<g, dim3(128), 0, stream>>>(x, damp, decay, ema, proj, rw, mask,
                                                      fwdP, bwdP, out);
    } else {
        dim3 grid(D / 16, B);
        dim3 block(64);
        ema_fwd_kernel<<<grid, block, 0, stream>>>(x, damp, decay, ema, proj, rw, mask, out);
        ema_bwd_kernel<<<grid, block, 0, stream>>>(x, damp, decay, ema, proj, rw, mask, out);
    }
}

// Round 13
// 191.442 us; speedup vs baseline: 17.6065x; 17.6065x over previous
//
#include <hip/hip_runtime.h>
#include <math.h>

#define L 2048
#define B 8
#define D 1024
#define ND 16
#define BD (B*D)
#define CK 64                 // chunk length
#define NC (L/CK)             // 32 chunks
#define SZ ((size_t)B*NC*D*ND)        // floats per direction (16.8 MB)

typedef float v2f __attribute__((ext_vector_type(2)));

__device__ __forceinline__ float sigmoid_precise(float v) {
    return 1.0f / (1.0f + expf(-v));
}
// fast sigmoid: v_exp + v_rcp (~3e-7 rel err; tolerance is 0.0625 abs)
__device__ __forceinline__ float sigmoid_fast(float v) {
    return __builtin_amdgcn_rcpf(1.0f + __expf(-v));
}

// Per-mode decay packed as 8 x float2 (modes 2i,2i+1 in lanes .x/.y).
__device__ __forceinline__ void load_q2(const float* __restrict__ damp,
                                        const float* __restrict__ decay,
                                        int row, v2f* q2) {
#pragma unroll
    for (int mg = 0; mg < 4; ++mg) {
        const float4 dp = reinterpret_cast<const float4*>(damp)[row * 4 + mg];
        const float4 dc = reinterpret_cast<const float4*>(decay)[row * 4 + mg];
        const float qa = 1.f - sigmoid_fast(dp.x) * sigmoid_fast(dc.x);
        const float qb = 1.f - sigmoid_fast(dp.y) * sigmoid_fast(dc.y);
        const float qc = 1.f - sigmoid_fast(dp.z) * sigmoid_fast(dc.z);
        const float qd = 1.f - sigmoid_fast(dp.w) * sigmoid_fast(dc.w);
        q2[2*mg+0] = (v2f){qa, qb};
        q2[2*mg+1] = (v2f){qc, qd};
    }
}

// Packed decay q2[8] and output coefficient c2[8] (= p * ema * proj / sqrt(ND)).
__device__ __forceinline__ void load_qc2(const float* __restrict__ damp,
                                         const float* __restrict__ decay,
                                         const float* __restrict__ ema,
                                         const float* __restrict__ proj,
                                         int row, v2f* q2, v2f* c2) {
#pragma unroll
    for (int mg = 0; mg < 4; ++mg) {
        const float4 dp = reinterpret_cast<const float4*>(damp)[row * 4 + mg];
        const float4 dc = reinterpret_cast<const float4*>(decay)[row * 4 + mg];
        const float4 em = reinterpret_cast<const float4*>(ema)[row * 4 + mg];
        const float4 pj = reinterpret_cast<const float4*>(proj)[row * 4 + mg];
        const float p0 = sigmoid_fast(dp.x), p1 = sigmoid_fast(dp.y),
                    p2 = sigmoid_fast(dp.z), p3 = sigmoid_fast(dp.w);
        q2[2*mg+0] = (v2f){1.f - p0 * sigmoid_fast(dc.x), 1.f - p1 * sigmoid_fast(dc.y)};
        q2[2*mg+1] = (v2f){1.f - p2 * sigmoid_fast(dc.z), 1.f - p3 * sigmoid_fast(dc.w)};
        c2[2*mg+0] = (v2f){p0 * em.x * pj.x * 0.25f, p1 * em.y * pj.y * 0.25f};
        c2[2*mg+1] = (v2f){p2 * em.z * pj.z * 0.25f, p3 * em.w * pj.w * 0.25f};
    }
}

// ---------------- Phase A: per-chunk local states (both directions) ----------
// Block = 128 threads: wave 0 scans forward (u = i), wave 1 backward
// (u = i ^ (CK-1)). Software-pipelined 3-buffer prefetch (fully flattened,
// static register indexing only -> ~100 VGPR, no spill). Masks staged to LDS
// once per block. Packed float2 mode math (v_pk_fma_f32).
__global__ __launch_bounds__(128, 2) void ema_summary_kernel(
    const float* __restrict__ x, const float* __restrict__ damp,
    const float* __restrict__ decay, const int* __restrict__ mask,
    float* __restrict__ fwdS, float* __restrict__ bwdS)
{
    __shared__ float smask[CK];
    const int lane = threadIdx.x & 63;
    const int wid  = threadIdx.x >> 6;          // 0 = fwd, 1 = bwd
    const int d  = blockIdx.x * 64 + lane;
    const int b  = blockIdx.y;
    const int ch = blockIdx.z;
    const int j0 = ch * CK;
    const int um = wid ? (CK - 1) : 0;          // u = i ^ um

    const float* xp = x + (size_t)j0 * BD + (size_t)b * D + d;
    const int*   mp = mask + (size_t)b * L + j0;
    if (threadIdx.x < CK) smask[threadIdx.x] = (float)mp[threadIdx.x];
    __syncthreads();

    const int row = wid ? (d + D) : d;
    v2f q2[8], st2[8];
    load_q2(damp, decay, row, q2);
#pragma unroll
    for (int k = 0; k < 8; ++k) st2[k] = (v2f){0.f, 0.f};

    float xA[16], xB[16], xC[16];
#define SLOADG(XR, G) \
    _Pragma("unroll") \
    for (int v = 0; v < 16; ++v) { \
        const int u = ((G) + v) ^ um; \
        XR[v] = xp[(size_t)u * BD]; \
    }
#define SCOMPG(XR, G) \
    _Pragma("unroll") \
    for (int v = 0; v < 16; ++v) { \
        const int u = ((G) + v) ^ um; \
        const float xm = XR[v] * smask[u]; \
        const v2f xm2 = {xm, xm}; \
        _Pragma("unroll") \
        for (int k = 0; k < 8; ++k) st2[k] = q2[k] * st2[k] + xm2; \
    }
    SLOADG(xA, 0)
    SLOADG(xB, 16)
    SLOADG(xC, 32)
    SCOMPG(xA, 0)
    SLOADG(xA, 48)
    SCOMPG(xB, 16)
    SCOMPG(xC, 32)
    SCOMPG(xA, 48)
#undef SLOADG
#undef SCOMPG

    float* Sx = wid ? bwdS : fwdS;
    float4* s4 = reinterpret_cast<float4*>(Sx) + ((size_t)(b * NC + ch) * D + d) * 4;
#pragma unroll
    for (int mg = 0; mg < 4; ++mg)
        s4[mg] = make_float4(st2[2*mg+0].x, st2[2*mg+0].y, st2[2*mg+1].x, st2[2*mg+1].y);
}

// ---------------- Phase B: prefix across chunks (in-place -> INCLUSIVE) ------
// One thread per (b, d, mode); 1024-thread blocks -> 4 KB contiguous segments
// per chunk index. All NC chunk values prefetched, then the two serial fma
// chains (fwd + bwd) interleaved for 2x chain ILP. Output layout: fwdS slot c
// holds the inclusive prefix through chunk c; bwdS slot c holds the inclusive
// suffix from chunk c (apply reads neighbor slots ch-1 / ch+1).
__global__ __launch_bounds__(1024) void ema_prefix_kernel(
    const float* __restrict__ damp, const float* __restrict__ decay,
    float* __restrict__ fwdS, float* __restrict__ bwdS)
{
    const int tid = blockIdx.x * 1024 + threadIdx.x;
    const int m = tid & (ND - 1);
    const int d = (tid >> 4) & (D - 1);
    const int b = tid >> 14;
    const size_t CS = (size_t)D * ND;
    const size_t off = (size_t)b * NC * CS + (size_t)d * ND + m;
    float* fb = fwdS + off;
    float* bb = bwdS + off;

    const int idxf = d * ND + m;
    const int idxb = (d + D) * ND + m;
    float qf = 1.f - sigmoid_fast(damp[idxf]) * sigmoid_fast(decay[idxf]);
    float qb = 1.f - sigmoid_fast(damp[idxb]) * sigmoid_fast(decay[idxb]);
#pragma unroll
    for (int s = 0; s < 6; ++s) { qf *= qf; qb *= qb; }   // q^64

    float Ef[NC], Eb[NC];
#pragma unroll
    for (int i = 0; i < NC; ++i) Ef[i] = fb[(size_t)i * CS];
#pragma unroll
    for (int i = 0; i < NC; ++i) Eb[i] = bb[(size_t)i * CS];

    float F = 0.f, G = 0.f;
#pragma unroll
    for (int i = 0; i < NC; ++i) {
        F = fmaf(qf, F, Ef[i]);          fb[(size_t)i * CS] = F;          // inclusive prefix
        G = fmaf(qb, G, Eb[NC-1-i]);     bb[(size_t)(NC-1-i) * CS] = G;   // inclusive suffix
    }
}

// ---------------- Phase C: apply (r9-proven; entry = neighbor inclusive slot) -
__global__ __launch_bounds__(128, 2) void ema_apply_kernel(
    const float* __restrict__ x, const float* __restrict__ damp,
    const float* __restrict__ decay, const float* __restrict__ ema,
    const float* __restrict__ proj, const float* __restrict__ rw,
    const int* __restrict__ mask,
    const float* __restrict__ fwdP, const float* __restrict__ bwdP,
    float* __restrict__ out)
{
    constexpr int HALF = CK / 2;
    __shared__ float hacc[2][HALF][64];      // 16 KB
    __shared__ float smask[CK];

    const int lane = threadIdx.x & 63;
    const int wid  = threadIdx.x >> 6;       // 0 = fwd, 1 = bwd
    const int d  = blockIdx.x * 64 + lane;
    const int b  = blockIdx.y;
    const int ch = blockIdx.z;
    const int j0 = ch * CK;
    const int um = wid ? (CK - 1) : 0;       // u = i ^ um

    const float* xp = x   + (size_t)j0 * BD + (size_t)b * D + d;
    float*       op = out + (size_t)j0 * BD + (size_t)b * D + d;
    const int*   mp = mask + (size_t)b * L + j0;
    if (threadIdx.x < CK) smask[threadIdx.x] = (float)mp[threadIdx.x];

    const int    row  = wid ? (d + D) : d;
    const float  weff = wid ? 0.f : rw[d];           // residual only on fwd wave
    const float* Sx   = wid ? bwdP : fwdP;

    v2f q2[8], c2[8], st2[8];
    load_qc2(damp, decay, ema, proj, row, q2, c2);
    // entry state: fwd chunk ch reads inclusive prefix slot ch-1;
    // bwd chunk ch reads inclusive suffix slot ch+1; boundary -> zeros.
    const int  eslot = wid ? (ch + 1) : (ch - 1);
    const bool ezero = wid ? (ch == NC - 1) : (ch == 0);
    if (!ezero) {
        const float4* s4 = reinterpret_cast<const float4*>(Sx) +
                           ((size_t)(b * NC + eslot) * D + d) * 4;
#pragma unroll
        for (int mg = 0; mg < 4; ++mg) {
            const float4 v = s4[mg];
            st2[2*mg+0] = (v2f){v.x, v.y};
            st2[2*mg+1] = (v2f){v.z, v.w};
        }
    } else {
#pragma unroll
        for (int k = 0; k < 8; ++k) st2[k] = (v2f){0.f, 0.f};
    }
    __syncthreads();   // smask visible

    float xA[16], xB[16], xC[16];

#define ALOADG(XR, G) \
    _Pragma("unroll") \
    for (int v = 0; v < 16; ++v) { \
        const int u = ((G) + v) ^ um; \
        XR[v] = xp[(size_t)u * BD]; \
    }
#define ASTEP(XR, V, G) \
    const int u = ((G) + (V)) ^ um; \
    const float xraw = XR[V]; \
    const float xm   = xraw * smask[u]; \
    const v2f xm2 = {xm, xm}; \
    _Pragma("unroll") \
    for (int k = 0; k < 8; ++k) st2[k] = q2[k] * st2[k] + xm2; \
    v2f a0 = c2[0] * st2[0], a1 = c2[1] * st2[1], \
        a2 = c2[2] * st2[2], a3 = c2[3] * st2[3]; \
    a0 = c2[4] * st2[4] + a0; \
    a1 = c2[5] * st2[5] + a1; \
    a2 = c2[6] * st2[6] + a2; \
    a3 = c2[7] * st2[7] + a3; \
    const v2f sres = (a0 + a1) + (a2 + a3);
#define ACOMP_LDS(XR, G) \
    _Pragma("unroll") \
    for (int v = 0; v < 16; ++v) { \
        ASTEP(XR, v, G) \
        hacc[wid][u & (HALF - 1)][lane] = fmaf(xraw, weff, sres.x + sres.y); \
    }
#define ACOMP_OUT(XR, G) \
    _Pragma("unroll") \
    for (int v = 0; v < 16; ++v) { \
        ASTEP(XR, v, G) \
        const float tv  = fmaf(xraw, weff, sres.x + sres.y); \
        const float val = tv + hacc[ow][u & (HALF - 1)][lane]; \
        op[(size_t)u * BD] = val * __builtin_amdgcn_rcpf(1.0f + __expf(-val)); \
    }

    // phase 1 (scan steps 0..31 -> LDS), with phase-2 loads already in flight
    ALOADG(xA, 0)
    ALOADG(xB, 16)
    ALOADG(xC, 32)
    ACOMP_LDS(xA, 0)
    ALOADG(xA, 48)
    ACOMP_LDS(xB, 16)
    __syncthreads();

    // phase 2 (scan steps 32..63): combine with other wave's half, silu, store
    const int ow = 1 - wid;
    ACOMP_OUT(xC, 32)
    ACOMP_OUT(xA, 48)
#undef ALOADG
#undef ASTEP
#undef ACOMP_LDS
#undef ACOMP_OUT
}

// ---------------- Fallback: validated single-pass scans ----------------------
template<int DIR>
__device__ __forceinline__ void ema_scan_body(
    const float* __restrict__ x, const float* __restrict__ damp,
    const float* __restrict__ decay, const float* __restrict__ ema,
    const float* __restrict__ proj, const float* __restrict__ rw,
    const int* __restrict__ mask, float* __restrict__ out)
{
    const int t  = threadIdx.x;
    const int ng = t & 3;
    const int dl = t >> 2;
    const int d  = blockIdx.x * 16 + dl;
    const int b  = blockIdx.y;
    const int row = (DIR == 0) ? d : (d + D);

    float q[4], c[4];
#pragma unroll
    for (int k = 0; k < 4; ++k) {
        const int idx = row * ND + ng * 4 + k;
        const float p  = sigmoid_precise(damp[idx]);
        const float sd = sigmoid_precise(decay[idx]);
        q[k] = 1.0f - p * sd;
        c[k] = p * ema[idx] * proj[idx] * 0.25f;
    }
    const float w = rw[d];
    const float* xp = x + (size_t)b * D + d;
    float*       op = out + (size_t)b * D + d;
    const int*   mp = mask + (size_t)b * L;
    float s0 = 0.f, s1 = 0.f, s2 = 0.f, s3 = 0.f;

    for (int jj = 0; jj < L; jj += 4) {
        float xv[4], mf[4];
#pragma unroll
        for (int u = 0; u < 4; ++u) {
            const int j = (DIR == 0) ? (jj + u) : (L - 1 - (jj + u));
            xv[u] = xp[(size_t)j * BD];
            mf[u] = (float)mp[j];
        }
        float acc[4];
#pragma unroll
        for (int u = 0; u < 4; ++u) {
            const float xm = xv[u] * mf[u];
            s0 = fmaf(q[0], s0, xm);
            s1 = fmaf(q[1], s1, xm);
            s2 = fmaf(q[2], s2, xm);
            s3 = fmaf(q[3], s3, xm);
            acc[u] = fmaf(c[1], s1, c[0] * s0) + fmaf(c[3], s3, c[2] * s2);
        }
#pragma unroll
        for (int u = 0; u < 4; ++u) acc[u] += __shfl_xor(acc[u], 1);
#pragma unroll
        for (int u = 0; u < 4; ++u) acc[u] += __shfl_xor(acc[u], 2);
        if (ng == 0) {
#pragma unroll
            for (int u = 0; u < 4; ++u) {
                const int j = (DIR == 0) ? (jj + u) : (L - 1 - (jj + u));
                const size_t oi = (size_t)j * BD;
                if (DIR == 0) op[oi] = fmaf(xv[u], w, acc[u]);
                else { const float v = op[oi] + acc[u]; op[oi] = v / (1.0f + expf(-v)); }
            }
        }
    }
}

__global__ __launch_bounds__(64) void ema_fwd_kernel(
    const float* __restrict__ x, const float* __restrict__ damp,
    const float* __restrict__ decay, const float* __restrict__ ema,
    const float* __restrict__ proj, const float* __restrict__ rw,
    const int* __restrict__ mask, float* __restrict__ out)
{ ema_scan_body<0>(x, damp, decay, ema, proj, rw, mask, out); }

__global__ __launch_bounds__(64) void ema_bwd_kernel(
    const float* __restrict__ x, const float* __restrict__ damp,
    const float* __restrict__ decay, const float* __restrict__ ema,
    const float* __restrict__ proj, const float* __restrict__ rw,
    const int* __restrict__ mask, float* __restrict__ out)
{ ema_scan_body<1>(x, damp, decay, ema, proj, rw, mask, out); }

// ---------------- driver -----------------------------------------------------
extern "C" void kernel_launch(void* const* d_in, const int* in_sizes, int n_in,
                              void* d_out, int out_size, void* d_ws, size_t ws_size,
                              hipStream_t stream) {
    (void)in_sizes; (void)n_in; (void)out_size;
    const float* x     = (const float*)d_in[0];
    const float* damp  = (const float*)d_in[1];
    const float* decay = (const float*)d_in[2];
    const float* ema   = (const float*)d_in[3];
    const float* proj  = (const float*)d_in[4];
    const float* rw    = (const float*)d_in[5];
    const int*   mask  = (const int*)d_in[6];
    float* out = (float*)d_out;

    const size_t stateBytes = 2 * SZ * sizeof(float);   // 33.6 MB

    if (ws_size >= stateBytes) {
        float* fwdP = (float*)d_ws;
        float* bwdP = fwdP + SZ;
        dim3 g(D / 64, B, NC);
        ema_summary_kernel<<<g, dim3(128), 0, stream>>>(x, damp, decay, mask, fwdP, bwdP);
        ema_prefix_kernel<<<dim3((B * D * ND) / 1024), dim3(1024), 0, stream>>>(damp, decay, fwdP, bwdP);
        ema_apply_kernel<<<g, dim3(128), 0, stream>>>(x, damp, decay, ema, proj, rw, mask,
                                                      fwdP, bwdP, out);
    } else {
        dim3 grid(D / 16, B);
        dim3 block(64);
        ema_fwd_kernel<<<grid, block, 0, stream>>>(x, damp, decay, ema, proj, rw, mask, out);
        ema_bwd_kernel<<<grid, block, 0, stream>>>(x, damp, decay, ema, proj, rw, mask, out);
    }
}